// Round 3
// baseline (442.316 us; speedup 1.0000x reference)
//
#include <hip/hip_runtime.h>

// out[idx0[idx1[idx2[i]]]] = x[i]; all indices unique -> pure permutation scatter.
// Single-pass version: inverse map in workspace, then one streaming write of out.

typedef float f32x4 __attribute__((ext_vector_type(4)));   // clang-native: OK for nontemporal builtins
typedef int   i32x4 __attribute__((ext_vector_type(4)));

// ws layout: inv[V0] ints (V0 = out_size / 64)

__global__ void init_inv_kernel(i32x4* __restrict__ inv4, int n) {
    int i = blockIdx.x * blockDim.x + threadIdx.x;
    if (i < n) {
        i32x4 m = {-1, -1, -1, -1};
        inv4[i] = m;
    }
}

__global__ void build_inv_kernel(const int* __restrict__ idx0,
                                 const int* __restrict__ idx1,
                                 const int* __restrict__ idx2,
                                 int* __restrict__ inv, int n3) {
    int i = blockIdx.x * blockDim.x + threadIdx.x;
    if (i < n3) {
        int j2 = idx2[i];
        int j1 = idx1[j2];
        int j0 = idx0[j1];
        inv[j0] = i;   // indices are unique: no collisions
    }
}

__global__ void write_out_kernel(const f32x4* __restrict__ x,
                                 const int* __restrict__ inv,
                                 f32x4* __restrict__ out,
                                 long n4) {
    long i = (long)blockIdx.x * blockDim.x + threadIdx.x;
    if (i >= n4) return;
    int r = inv[i >> 4];                 // 16 consecutive lanes share one inv entry
    f32x4 v = {0.f, 0.f, 0.f, 0.f};
    if (r >= 0) v = x[(long)r * 16 + (i & 15)];
    __builtin_nontemporal_store(v, &out[i]);   // streaming store: no reuse, keep L2 clean
}

extern "C" void kernel_launch(void* const* d_in, const int* in_sizes, int n_in,
                              void* d_out, int out_size, void* d_ws, size_t ws_size,
                              hipStream_t stream) {
    // setup_inputs order: x, idx0, idx1, idx2, v0, v1, v2
    const float* x    = (const float*)d_in[0];
    const int*   idx0 = (const int*)d_in[1];
    const int*   idx1 = (const int*)d_in[2];
    const int*   idx2 = (const int*)d_in[3];
    float* out = (float*)d_out;

    const int n3 = in_sizes[3];              // 25000 rows of x
    const int F  = in_sizes[0] / n3;         // 64
    const int v0 = out_size / F;             // 1,600,000 output rows

    int* inv = (int*)d_ws;                   // v0 ints = 6.4 MB

    // 1) inv = -1 (6.4 MB, ~2 us)
    int n_i4 = v0 / 4;
    init_inv_kernel<<<(n_i4 + 255) / 256, 256, 0, stream>>>((i32x4*)inv, n_i4);

    // 2) inv[compose(i)] = i (25000 threads)
    build_inv_kernel<<<(n3 + 255) / 256, 256, 0, stream>>>(idx0, idx1, idx2, inv, n3);

    // 3) single streaming pass over out: 409.6 MB written exactly once
    long n4 = (long)out_size / 4;
    write_out_kernel<<<(int)((n4 + 255) / 256), 256, 0, stream>>>(
        (const f32x4*)x, inv, (f32x4*)out, n4);
}

// Round 4
// 440.284 us; speedup vs baseline: 1.0046x; 1.0046x over previous
//
#include <hip/hip_runtime.h>

// out[idx0[idx1[idx2[i]]]] = x[i]; all indices unique -> pure permutation scatter.
// Single-pass: inverse map in workspace, then ONE streaming write of out with
// PLAIN stores (R3 lesson: nontemporal 'nt' stores bypass L2 write-combining on
// gfx950 and drop streaming-write BW from ~6.2 to ~2.5 TB/s — don't use them here).

typedef float f32x4 __attribute__((ext_vector_type(4)));
typedef int   i32x4 __attribute__((ext_vector_type(4)));

// ws layout: inv[V0] ints (V0 = out_size / 64)

__global__ void init_inv_kernel(i32x4* __restrict__ inv4, int n) {
    int i = blockIdx.x * blockDim.x + threadIdx.x;
    if (i < n) {
        i32x4 m = {-1, -1, -1, -1};
        inv4[i] = m;
    }
}

__global__ void build_inv_kernel(const int* __restrict__ idx0,
                                 const int* __restrict__ idx1,
                                 const int* __restrict__ idx2,
                                 int* __restrict__ inv, int n3) {
    int i = blockIdx.x * blockDim.x + threadIdx.x;
    if (i < n3) {
        int j2 = idx2[i];
        int j1 = idx1[j2];
        int j0 = idx0[j1];
        inv[j0] = i;   // indices are unique: no collisions
    }
}

__global__ void write_out_kernel(const f32x4* __restrict__ x,
                                 const int* __restrict__ inv,
                                 f32x4* __restrict__ out,
                                 long n4) {
    long i = (long)blockIdx.x * blockDim.x + threadIdx.x;
    if (i >= n4) return;
    int r = inv[i >> 4];                 // 16 consecutive lanes share one inv entry
    f32x4 v = {0.f, 0.f, 0.f, 0.f};
    if (r >= 0) v = x[(long)r * 16 + (i & 15)];
    out[i] = v;                          // plain store: L2 write-combined, full BW
}

extern "C" void kernel_launch(void* const* d_in, const int* in_sizes, int n_in,
                              void* d_out, int out_size, void* d_ws, size_t ws_size,
                              hipStream_t stream) {
    // setup_inputs order: x, idx0, idx1, idx2, v0, v1, v2
    const float* x    = (const float*)d_in[0];
    const int*   idx0 = (const int*)d_in[1];
    const int*   idx1 = (const int*)d_in[2];
    const int*   idx2 = (const int*)d_in[3];
    float* out = (float*)d_out;

    const int n3 = in_sizes[3];              // 25000 rows of x
    const int F  = in_sizes[0] / n3;         // 64
    const int v0 = out_size / F;             // 1,600,000 output rows

    int* inv = (int*)d_ws;                   // v0 ints = 6.4 MB

    // 1) inv = -1 (6.4 MB, ~2 us)
    int n_i4 = v0 / 4;
    init_inv_kernel<<<(n_i4 + 255) / 256, 256, 0, stream>>>((i32x4*)inv, n_i4);

    // 2) inv[compose(i)] = i (25000 threads)
    build_inv_kernel<<<(n3 + 255) / 256, 256, 0, stream>>>(idx0, idx1, idx2, inv, n3);

    // 3) single streaming pass over out: 409.6 MB written exactly once
    long n4 = (long)out_size / 4;
    write_out_kernel<<<(int)((n4 + 255) / 256), 256, 0, stream>>>(
        (const f32x4*)x, inv, (f32x4*)out, n4);
}

// Round 5
// 422.348 us; speedup vs baseline: 1.0473x; 1.0425x over previous
//
#include <hip/hip_runtime.h>

// out[idx0[idx1[idx2[i]]]] = x[i]; indices unique -> pure permutation scatter.
// R4 lesson: single-pass (load inv + store per float4) = 2 VMEM instr / 16 B,
// which caps at ~4.9 TB/s (VMEM issue rate), BELOW the 6.2 TB/s HBM write
// ceiling. Two-kernel structure keeps the big pass at 1 instr / 16 B:
//   1) zero-fill out (409.6 MB, store-only, fill-speed ~66 us)
//   2) scatter 25000 rows (12.8 MB, ~5 us)

typedef float f32x4 __attribute__((ext_vector_type(4)));

// 4 stores per thread, block-strided so each store instruction is perfectly
// coalesced (consecutive lanes -> consecutive 16 B).
__global__ void zero_out_kernel(f32x4* __restrict__ out, long n4) {
    long base = (long)blockIdx.x * (blockDim.x * 4) + threadIdx.x;
    f32x4 z = {0.f, 0.f, 0.f, 0.f};
    #pragma unroll
    for (int j = 0; j < 4; ++j) {
        long i = base + (long)j * blockDim.x;
        if (i < n4) out[i] = z;
    }
}

__global__ void scatter_rows_kernel(const f32x4* __restrict__ x,
                                    const int* __restrict__ idx0,
                                    const int* __restrict__ idx1,
                                    const int* __restrict__ idx2,
                                    f32x4* __restrict__ out,
                                    int n3) {
    int t = blockIdx.x * blockDim.x + threadIdx.x;
    int row = t >> 4;    // 16 float4 per 64-float row
    int c   = t & 15;
    if (row >= n3) return;
    // compose the three collision-free scatters: deepest first
    int j2 = idx2[row];
    int j1 = idx1[j2];
    int j0 = idx0[j1];
    out[(long)j0 * 16 + c] = x[(long)row * 16 + c];
}

extern "C" void kernel_launch(void* const* d_in, const int* in_sizes, int n_in,
                              void* d_out, int out_size, void* d_ws, size_t ws_size,
                              hipStream_t stream) {
    // setup_inputs order: x, idx0, idx1, idx2, v0, v1, v2
    const float* x    = (const float*)d_in[0];
    const int*   idx0 = (const int*)d_in[1];
    const int*   idx1 = (const int*)d_in[2];
    const int*   idx2 = (const int*)d_in[3];
    float* out = (float*)d_out;

    const int n3 = in_sizes[3];          // 25000 rows of x

    // 1) zero the whole output: 409.6 MB, store-only, 1 instr / 16 B
    long n4 = (long)out_size / 4;        // number of float4 elements
    long per_block = 256 * 4;
    int  zblocks = (int)((n4 + per_block - 1) / per_block);
    zero_out_kernel<<<zblocks, 256, 0, stream>>>((f32x4*)out, n4);

    // 2) scatter the 25000 rows (6.4 MB read + 6.4 MB write)
    int total = n3 * 16;                 // one thread per float4 of x
    int sblocks = (total + 255) / 256;
    scatter_rows_kernel<<<sblocks, 256, 0, stream>>>(
        (const f32x4*)x, idx0, idx1, idx2, (f32x4*)out, n3);
}

// Round 6
// 406.658 us; speedup vs baseline: 1.0877x; 1.0386x over previous
//
#include <hip/hip_runtime.h>

// MultiBackScatter: out[idx0[idx1[idx2[i]]]] = x[i]; index arrays are prefixes
// of permutations -> all unique -> the three chained scatter-adds collapse to a
// single collision-free permutation scatter of 25000 rows into a zeroed [V0,64].
//
// Measured structure facts (R1-R5 on this MI355X):
//  - fill ceiling ~6.2-6.3 TB/s (harness fillBufferAligned reference)
//  - mandatory traffic: 409.6 MB out-write + 12.8 MB scatter = ~67 us floor
//  - single-pass inv-map variant is SLOWER (2 VMEM instr/16 B caps at ~4.2 TB/s,
//    R3/R4) -> keep the big pass store-only at 1 instr/16 B.
//  - nontemporal stores: no effect (R3 vs R4).
//  - 4x unroll of the fill: no effect beyond noise (R5).

__global__ void zero_out_kernel(float4* __restrict__ out, long n4) {
    long i = (long)blockIdx.x * blockDim.x + threadIdx.x;
    if (i < n4) {
        out[i] = make_float4(0.f, 0.f, 0.f, 0.f);
    }
}

__global__ void scatter_rows_kernel(const float4* __restrict__ x,
                                    const int* __restrict__ idx0,
                                    const int* __restrict__ idx1,
                                    const int* __restrict__ idx2,
                                    float4* __restrict__ out,
                                    int n3) {
    int t = blockIdx.x * blockDim.x + threadIdx.x;
    int row = t >> 4;    // 16 float4 per 64-float row
    int c   = t & 15;
    if (row >= n3) return;
    // compose the three collision-free scatters: deepest first
    int j2 = idx2[row];   // position in [0, V2)
    int j1 = idx1[j2];    // position in [0, V1)
    int j0 = idx0[j1];    // position in [0, V0)
    out[(long)j0 * 16 + c] = x[(long)row * 16 + c];
}

extern "C" void kernel_launch(void* const* d_in, const int* in_sizes, int n_in,
                              void* d_out, int out_size, void* d_ws, size_t ws_size,
                              hipStream_t stream) {
    // setup_inputs order: x, idx0, idx1, idx2, v0, v1, v2
    const float* x    = (const float*)d_in[0];
    const int*   idx0 = (const int*)d_in[1];
    const int*   idx1 = (const int*)d_in[2];
    const int*   idx2 = (const int*)d_in[3];
    float* out = (float*)d_out;

    const int n3 = in_sizes[3];          // 25000 rows of x

    // 1) zero the whole output (409.6 MB, store-only, fill-speed)
    long n4 = (long)out_size / 4;        // number of float4 elements (grid divides evenly)
    int  zblocks = (int)((n4 + 255) / 256);
    zero_out_kernel<<<zblocks, 256, 0, stream>>>((float4*)out, n4);

    // 2) scatter the 25000 rows (6.4 MB read + 6.4 MB write)
    int total = n3 * 16;                 // one thread per float4 of x
    int sblocks = (total + 255) / 256;
    scatter_rows_kernel<<<sblocks, 256, 0, stream>>>(
        (const float4*)x, idx0, idx1, idx2, (float4*)out, n3);
}